// Round 1
// 1598.840 us; speedup vs baseline: 1.1071x; 1.1071x over previous
//
#include <hip/hip_runtime.h>

// noiseRNN: h_t = tanh(x_t @ w_ih.T + b_ih + h_{t-1} @ w_hh.T + b_hh)
//           out_t = h_t ; carry = h_t + 0.1*noise_t
// T=2048 B=256 I=64 H=128, fp32. Grid = 256 (one WG per batch element).
// Block = 256 = 4 waves. K(=192 augmented) split 4-way across waves (48/wave),
// each thread owns row pair (2l, 2l+1) with its 48-wide weight slice in VGPRs.
//
// vs previous version:
//  - __launch_bounds__(256,1): grid is 1 WG/CU so occupancy is fixed at 4 waves/CU;
//    without the ",1" the compiler capped VGPRs at 68 and re-streamed the 96
//    weight floats/thread from L1/L2 every step (~1700 cyc/step = the measured time).
//  - ONE barrier per step (raw s_barrier, no vmcnt drain): reduce is done
//    redundantly by all 4 waves (identical values, double-buffered part/aug =>
//    race-free with a single rendezvous per step).
//  - depth-2 prefetch of noise/x so HBM latency (~900cy) is fully covered and
//    never drained at a barrier.
//  - branch-free fast tanh on the serial chain.

constexpr int T_ = 2048;
constexpr int B_ = 256;
constexpr int I_ = 64;
constexpr int H_ = 128;
constexpr int BH_ = B_ * H_;     // 32768
constexpr int BI_ = B_ * I_;     // 16384
constexpr long long TBH_ = (long long)T_ * BH_;  // 67108864
constexpr float STD_ = 0.1f;
constexpr int AUG_ = H_ + I_;    // 192 augmented K dim
constexpr int JPT_ = AUG_ / 4;   // 48 K-elems per wave slice
constexpr int PSTR_ = 132;       // partial row stride in floats (conflict-free)

__device__ __forceinline__ float tanh_fast(float s) {
    // tanh(s) = 1 - 2/(exp(2s)+1); robust: e=inf -> 1, e=0 -> -1. ~2ulp.
    const float e = __expf(2.0f * s);
    return 1.0f - __fdividef(2.0f, e + 1.0f);
}

// LDS-visibility barrier WITHOUT the vmcnt(0) drain __syncthreads would emit:
// global prefetch loads / output stores stay in flight across the rendezvous.
#define BAR() asm volatile("s_waitcnt lgkmcnt(0)\n\ts_barrier" ::: "memory")

__global__ __launch_bounds__(256, 1)
void rnn_scan(const float* __restrict__ x, const float* __restrict__ w_ih,
              const float* __restrict__ w_hh, const float* __restrict__ b_ih,
              const float* __restrict__ b_hh, const float* __restrict__ noise,
              const float* __restrict__ h0, float* __restrict__ out)
{
    __shared__ __align__(16) float aug[2][AUG_];        // [h(+noise) | x_t], dbuf
    __shared__ __align__(16) float part[2][4 * PSTR_];  // per-wave partials, dbuf

    const int b   = blockIdx.x;
    const int tid = threadIdx.x;
    const int q   = tid >> 6;          // wave id = K-slice id
    const int l   = tid & 63;
    const int r0  = 2 * l;             // this thread's output rows: r0, r0+1
    const int j0  = q * JPT_;

    // ---- augmented weight slices into registers (96 VGPRs, resident) ----
    float W0[JPT_], W1[JPT_];
#pragma unroll
    for (int jj = 0; jj < JPT_; ++jj) {
        const int j = j0 + jj;
        if (j < H_) {
            W0[jj] = w_hh[r0 * H_ + j];
            W1[jj] = w_hh[(r0 + 1) * H_ + j];
        } else {
            W0[jj] = w_ih[r0 * I_ + (j - H_)];
            W1[jj] = w_ih[(r0 + 1) * I_ + (j - H_)];
        }
    }

    const float bias0 = b_ih[r0] + b_hh[r0];
    const float bias1 = b_ih[r0 + 1] + b_hh[r0 + 1];

    // ---- init buffer 0 (each wave writes the FULL buffer it will read: no sync) ----
    {
        const float2 h00 = *(const float2*)&h0[b * H_ + r0];
        *(float2*)&aug[0][r0] = h00;
        aug[0][H_ + l] = x[b * I_ + l];            // x(0)
    }

    // ---- prefetch pipeline: step t consumes noise(t) and x(t+1); depth 2 ----
    float2 nv_c = *(const float2*)&noise[(long long)0 * BH_ + b * H_ + r0];
    float2 nv_n = *(const float2*)&noise[(long long)1 * BH_ + b * H_ + r0];
    float  xv_c = x[(long long)1 * BI_ + b * I_ + l];
    float  xv_n = x[(long long)2 * BI_ + b * I_ + l];

    for (int t = 0; t < T_; ++t) {
        const int p  = t & 1;
        const int np = p ^ 1;

        // issue next prefetches first: in flight across the whole step (~2 steps cover)
        float2 nv_f = make_float2(0.0f, 0.0f);
        float  xv_f = 0.0f;
        if (t + 2 < T_) nv_f = *(const float2*)&noise[(long long)(t + 2) * BH_ + b * H_ + r0];
        if (t + 3 < T_) xv_f = x[(long long)(t + 3) * BI_ + b * I_ + l];

        // ---- dot over this wave's K-slice (broadcast float4 LDS reads) ----
        float p0 = 0.0f, p1 = 0.0f;
        const float* ap = &aug[p][j0];
#pragma unroll
        for (int i = 0; i < JPT_ / 4; ++i) {
            const float4 v = *(const float4*)(ap + 4 * i);
            p0 = fmaf(v.x, W0[4 * i + 0], p0);  p1 = fmaf(v.x, W1[4 * i + 0], p1);
            p0 = fmaf(v.y, W0[4 * i + 1], p0);  p1 = fmaf(v.y, W1[4 * i + 1], p1);
            p0 = fmaf(v.z, W0[4 * i + 2], p0);  p1 = fmaf(v.z, W1[4 * i + 2], p1);
            p0 = fmaf(v.w, W0[4 * i + 3], p0);  p1 = fmaf(v.w, W1[4 * i + 3], p1);
        }
        *(float2*)&part[p][q * PSTR_ + r0] = make_float2(p0, p1);

        BAR();   // single rendezvous per step; partials(t) now visible

        // ---- redundant reduce: EVERY wave computes all 128 h values ----
        const float2 a0 = *(const float2*)&part[p][0 * PSTR_ + r0];
        const float2 a1 = *(const float2*)&part[p][1 * PSTR_ + r0];
        const float2 a2 = *(const float2*)&part[p][2 * PSTR_ + r0];
        const float2 a3 = *(const float2*)&part[p][3 * PSTR_ + r0];
        const float s0 = (a0.x + a1.x) + (a2.x + a3.x) + bias0;
        const float s1 = (a0.y + a1.y) + (a2.y + a3.y) + bias1;
        const float hn0 = tanh_fast(s0);
        const float hn1 = tanh_fast(s1);

        if (q == 0)  // only wave 0 stores (others' values are bitwise identical)
            *(float2*)&out[(long long)t * BH_ + b * H_ + r0] = make_float2(hn0, hn1);

        const float hx0 = fmaf(STD_, nv_c.x, hn0);
        const float hx1 = fmaf(STD_, nv_c.y, hn1);
        // each wave writes the FULL next-state buffer it will read (benign
        // identical-value races with other waves; self-consistent without sync)
        *(float2*)&aug[np][r0] = make_float2(hx0, hx1);
        aug[np][H_ + l] = xv_c;                      // x(t+1)

        if (t == T_ - 1 && q == 0)
            *(float2*)&out[TBH_ + b * H_ + r0] = make_float2(hx0, hx1);

        nv_c = nv_n; nv_n = nv_f;
        xv_c = xv_n; xv_n = xv_f;
    }
}

extern "C" void kernel_launch(void* const* d_in, const int* in_sizes, int n_in,
                              void* d_out, int out_size, void* d_ws, size_t ws_size,
                              hipStream_t stream) {
    const float* x     = (const float*)d_in[0];
    const float* w_ih  = (const float*)d_in[1];
    const float* w_hh  = (const float*)d_in[2];
    const float* b_ih  = (const float*)d_in[3];
    const float* b_hh  = (const float*)d_in[4];
    const float* noise = (const float*)d_in[5];
    const float* h0    = (const float*)d_in[6];
    float* outp        = (float*)d_out;

    rnn_scan<<<dim3(B_), dim3(256), 0, stream>>>(x, w_ih, w_hh, b_ih, b_hh,
                                                 noise, h0, outp);
}

// Round 2
// 1525.338 us; speedup vs baseline: 1.1605x; 1.0482x over previous
//
#include <hip/hip_runtime.h>

// noiseRNN: h_t = tanh(x_t @ w_ih.T + b_ih + h_{t-1} @ w_hh.T + b_hh)
//           out_t = h_t ; carry = h_t + 0.1*noise_t
// T=2048 B=256 I=64 H=128, fp32. Grid = 256 (one WG per batch element).
// Block = 256 = 4 waves. K(=192 augmented) split 4-way across waves (48/wave),
// each thread owns row pair (2l, 2l+1) with its 48-wide weight slice in VGPRs.
//
// vs previous version: weights are now 24 NAMED float4 variables (no arrays —
// SROA cannot fail) and each component is pinned with a volatile asm after
// load, so the compiler can neither rematerialize the loads inside the t-loop
// nor park the values in scratch. Previous versions showed VGPR_Count=68..72:
// the 96 weight floats/thread were being re-streamed from L2 every step
// (~96KB/CU/step / 56B-per-cyc ≈ 1700 cyc/step = the entire measured time).

constexpr int T_ = 2048;
constexpr int B_ = 256;
constexpr int I_ = 64;
constexpr int H_ = 128;
constexpr int BH_ = B_ * H_;     // 32768
constexpr int BI_ = B_ * I_;     // 16384
constexpr long long TBH_ = (long long)T_ * BH_;  // 67108864
constexpr float STD_ = 0.1f;
constexpr int AUG_ = H_ + I_;    // 192 augmented K dim
constexpr int JPT_ = AUG_ / 4;   // 48 K-elems per wave slice
constexpr int PSTR_ = 132;       // partial row stride in floats (conflict-free)

__device__ __forceinline__ float tanh_fast(float s) {
    // tanh(s) = 1 - 2/(exp(2s)+1); robust: e=inf -> 1, e=0 -> -1.
    const float e = __expf(2.0f * s);
    return 1.0f - __fdividef(2.0f, e + 1.0f);
}

// LDS-visibility barrier WITHOUT the vmcnt(0) drain __syncthreads would emit:
// global prefetch loads / output stores stay in flight across the rendezvous.
#define BAR() asm volatile("s_waitcnt lgkmcnt(0)\n\ts_barrier" ::: "memory")

// Pin a float4's components into VGPRs: volatile asm output cannot be
// rematerialized, so the values must stay live for the whole kernel.
#define PIN4(v) asm volatile("" : "+v"(v.x), "+v"(v.y), "+v"(v.z), "+v"(v.w))

__global__ __launch_bounds__(256, 1)
void rnn_scan(const float* __restrict__ x, const float* __restrict__ w_ih,
              const float* __restrict__ w_hh, const float* __restrict__ b_ih,
              const float* __restrict__ b_hh, const float* __restrict__ noise,
              const float* __restrict__ h0, float* __restrict__ out)
{
    __shared__ __align__(16) float aug[2][AUG_];        // [h(+noise) | x_t], dbuf
    __shared__ __align__(16) float part[2][4 * PSTR_];  // per-wave partials, dbuf

    const int b   = blockIdx.x;
    const int tid = threadIdx.x;
    const int q   = tid >> 6;          // wave id = K-slice id
    const int l   = tid & 63;
    const int r0  = 2 * l;             // this thread's output rows: r0, r0+1
    const int j0  = q * JPT_;

    // ---- augmented weight slices: 24 named float4s (96 VGPRs, resident) ----
    // Every 16B chunk of the slice lies wholly in w_hh (j<128) or w_ih (j>=128),
    // and both are float4-aligned (H=128, I=64, j0 multiple of 48 -> 4k offsets).
    float4 A0,A1,A2,A3,A4,A5,A6,A7,A8,A9,A10,A11;   // row r0
    float4 B0,B1,B2,B3,B4,B5,B6,B7,B8,B9,B10,B11;   // row r0+1
#define LD(k) { \
        const int j = j0 + 4*(k); \
        const float* s0 = (j < H_) ? (w_hh + r0*H_ + j) : (w_ih + r0*I_ + (j - H_)); \
        const float* s1 = (j < H_) ? (w_hh + (r0+1)*H_ + j) : (w_ih + (r0+1)*I_ + (j - H_)); \
        A##k = *(const float4*)s0; B##k = *(const float4*)s1; }
    LD(0) LD(1) LD(2) LD(3) LD(4) LD(5) LD(6) LD(7) LD(8) LD(9) LD(10) LD(11)
#undef LD
    PIN4(A0); PIN4(A1); PIN4(A2); PIN4(A3); PIN4(A4); PIN4(A5);
    PIN4(A6); PIN4(A7); PIN4(A8); PIN4(A9); PIN4(A10); PIN4(A11);
    PIN4(B0); PIN4(B1); PIN4(B2); PIN4(B3); PIN4(B4); PIN4(B5);
    PIN4(B6); PIN4(B7); PIN4(B8); PIN4(B9); PIN4(B10); PIN4(B11);

    const float bias0 = b_ih[r0] + b_hh[r0];
    const float bias1 = b_ih[r0 + 1] + b_hh[r0 + 1];

    // ---- init buffer 0 (each wave writes the FULL buffer it will read: no sync) ----
    {
        const float2 h00 = *(const float2*)&h0[b * H_ + r0];
        *(float2*)&aug[0][r0] = h00;
        aug[0][H_ + l] = x[b * I_ + l];            // x(0)
    }

    // ---- prefetch pipeline: step t consumes noise(t) and x(t+1); depth 2 ----
    float2 nv_c = *(const float2*)&noise[(long long)0 * BH_ + b * H_ + r0];
    float2 nv_n = *(const float2*)&noise[(long long)1 * BH_ + b * H_ + r0];
    float  xv_c = x[(long long)1 * BI_ + b * I_ + l];
    float  xv_n = x[(long long)2 * BI_ + b * I_ + l];

    for (int t = 0; t < T_; ++t) {
        const int p  = t & 1;
        const int np = p ^ 1;

        // issue next prefetches first: in flight across the whole step
        float2 nv_f = make_float2(0.0f, 0.0f);
        float  xv_f = 0.0f;
        if (t + 2 < T_) nv_f = *(const float2*)&noise[(long long)(t + 2) * BH_ + b * H_ + r0];
        if (t + 3 < T_) xv_f = x[(long long)(t + 3) * BI_ + b * I_ + l];

        // ---- dot over this wave's K-slice (broadcast float4 LDS reads) ----
        float p0 = 0.0f, p1 = 0.0f;
        const float* ap = &aug[p][j0];
#define DOT(k) { const float4 v = *(const float4*)(ap + 4*(k)); \
        p0 = fmaf(v.x, A##k.x, p0);  p1 = fmaf(v.x, B##k.x, p1); \
        p0 = fmaf(v.y, A##k.y, p0);  p1 = fmaf(v.y, B##k.y, p1); \
        p0 = fmaf(v.z, A##k.z, p0);  p1 = fmaf(v.z, B##k.z, p1); \
        p0 = fmaf(v.w, A##k.w, p0);  p1 = fmaf(v.w, B##k.w, p1); }
        DOT(0) DOT(1) DOT(2) DOT(3) DOT(4) DOT(5)
        DOT(6) DOT(7) DOT(8) DOT(9) DOT(10) DOT(11)
#undef DOT
        *(float2*)&part[p][q * PSTR_ + r0] = make_float2(p0, p1);

        BAR();   // single rendezvous per step; partials(t) now visible

        // ---- redundant reduce: EVERY wave computes all 128 h values ----
        const float2 a0 = *(const float2*)&part[p][0 * PSTR_ + r0];
        const float2 a1 = *(const float2*)&part[p][1 * PSTR_ + r0];
        const float2 a2 = *(const float2*)&part[p][2 * PSTR_ + r0];
        const float2 a3 = *(const float2*)&part[p][3 * PSTR_ + r0];
        const float s0 = (a0.x + a1.x) + (a2.x + a3.x) + bias0;
        const float s1 = (a0.y + a1.y) + (a2.y + a3.y) + bias1;
        const float hn0 = tanh_fast(s0);
        const float hn1 = tanh_fast(s1);

        if (q == 0)  // only wave 0 stores (others' values are bitwise identical)
            *(float2*)&out[(long long)t * BH_ + b * H_ + r0] = make_float2(hn0, hn1);

        const float hx0 = fmaf(STD_, nv_c.x, hn0);
        const float hx1 = fmaf(STD_, nv_c.y, hn1);
        // each wave writes the FULL next-state buffer it will read (benign
        // identical-value races with other waves; self-consistent without sync)
        *(float2*)&aug[np][r0] = make_float2(hx0, hx1);
        aug[np][H_ + l] = xv_c;                      // x(t+1)

        if (t == T_ - 1 && q == 0)
            *(float2*)&out[TBH_ + b * H_ + r0] = make_float2(hx0, hx1);

        nv_c = nv_n; nv_n = nv_f;
        xv_c = xv_n; xv_n = xv_f;
    }
}

extern "C" void kernel_launch(void* const* d_in, const int* in_sizes, int n_in,
                              void* d_out, int out_size, void* d_ws, size_t ws_size,
                              hipStream_t stream) {
    const float* x     = (const float*)d_in[0];
    const float* w_ih  = (const float*)d_in[1];
    const float* w_hh  = (const float*)d_in[2];
    const float* b_ih  = (const float*)d_in[3];
    const float* b_hh  = (const float*)d_in[4];
    const float* b5    = (const float*)d_in[5];
    const float* h0    = (const float*)d_in[6];
    float* outp        = (float*)d_out;

    rnn_scan<<<dim3(B_), dim3(256), 0, stream>>>(x, w_ih, w_hh, b_ih, b_hh,
                                                 b5, h0, outp);
}